// Round 1
// 794.473 us; speedup vs baseline: 1.0081x; 1.0081x over previous
//
#include <hip/hip_runtime.h>

// ---------------------------------------------------------------------------
// ManualMultiheadAttention: T=S=2048, B=2, H=16, D=64, E=1024
// out0 = [T,B,E] fp32, out1 = probs [B,H,T,S] fp32 (written once, nontemporal)
// v2: global_load_lds staging w/ XOR swizzle for all GEMM+attn tiles,
//     fused QKV GEMM (3 blocks/CU), double-buffered async K/V in attn,
//     V pre-transposed once in global, 5 launches total.
// ---------------------------------------------------------------------------

#define LDT 72  // padded LDS row stride (shorts) for Qs/Ps: 144 B, 2-way alias = free

typedef __attribute__((ext_vector_type(8))) short short8;
typedef __attribute__((ext_vector_type(4))) float f32x4;

union V16 { float4 f4; unsigned long long u64[2]; unsigned short us[8]; };

__device__ __forceinline__ unsigned short f2bf(float f) {
  union { float f; unsigned u; } v; v.f = f;
  unsigned u = v.u;
  u += 0x7FFFu + ((u >> 16) & 1u);   // round-to-nearest-even
  return (unsigned short)(u >> 16);
}

__device__ __forceinline__ short8 load8(const unsigned short* p) {  // 8 bf16, 8B-aligned
  union { short8 v; unsigned long long u[2]; } r;
  r.u[0] = *(const unsigned long long*)(p);
  r.u[1] = *(const unsigned long long*)(p + 4);
  return r.v;
}

__device__ __forceinline__ void st16(unsigned short* dst, V16 v) {
  *(unsigned long long*)(dst) = v.u64[0];
  *(unsigned long long*)(dst + 4) = v.u64[1];
}

// async global->LDS, 16B per lane. LDS dest = wave-uniform base + lane*16.
typedef const __attribute__((address_space(1))) void* gas_t;
typedef __attribute__((address_space(3))) void* las_t;
__device__ __forceinline__ void gld16(const void* g, void* l) {
  __builtin_amdgcn_global_load_lds((gas_t)g, (las_t)l, 16, 0, 0);
}

// ---------------------------------------------------------------------------
// One launch converts all five fp32 regions to bf16.
__global__ void cvt_all(const float* __restrict__ q, const float* __restrict__ k,
                        const float* __restrict__ v, const float* __restrict__ wi,
                        const float* __restrict__ wo,
                        unsigned short* __restrict__ oq, unsigned short* __restrict__ ok2,
                        unsigned short* __restrict__ ov, unsigned short* __restrict__ owi,
                        unsigned short* __restrict__ owo) {
  int y = blockIdx.y;
  const float* src; unsigned short* dst; int n;
  if (y == 0)      { src = q;  dst = oq;  n = 4194304; }
  else if (y == 1) { src = k;  dst = ok2; n = 4194304; }
  else if (y == 2) { src = v;  dst = ov;  n = 4194304; }
  else if (y == 3) { src = wi; dst = owi; n = 3145728; }
  else             { src = wo; dst = owo; n = 1048576; }
  int i = (blockIdx.x * 256 + threadIdx.x) * 4;
  if (i < n) {
    float4 f = *(const float4*)(src + i);
    ushort4 o;
    o.x = f2bf(f.x); o.y = f2bf(f.y); o.z = f2bf(f.z); o.w = f2bf(f.w);
    *(ushort4*)(dst + i) = o;
  }
}

// ---------------------------------------------------------------------------
// C[row,col] = sum_k A[row,k]*Bw[col,k] + bias[col].  128xBN tile, 4 waves.
// m97-style staging: global_load_lds dwordx4 into linear LDS [rows][64],
// source pre-swizzled (seg ^= row&7) so ds_read_b64 frag reads are conflict-free.
// qkv mode: blockIdx.x spans 3072 cols; col block selects A (Xq/Xk/Xv) and W slab.
template<int BN>
__global__ __launch_bounds__(256, 2) void gemm_bt(
    const unsigned short* __restrict__ A0,
    const unsigned short* __restrict__ A1,
    const unsigned short* __restrict__ A2,
    const unsigned short* __restrict__ W,
    const float* __restrict__ bias,
    void* __restrict__ Cv,
    int K, int ldc, int qkv)
{
  constexpr int NI = BN / 32;          // B frags per wave / B issues per wave
  __shared__ unsigned short As[128 * 64];
  __shared__ unsigned short Bs[BN * 64];
  int tid = threadIdx.x;
  int lane = tid & 63;
  int w = tid >> 6;
  int wm = (w & 1) * 64, wn = (w >> 1) * (BN / 2);
  int m0 = blockIdx.y * 128, n0g = blockIdx.x * BN;
  int which = qkv ? (n0g >> 10) : 0;
  const unsigned short* A = (which == 0) ? A0 : ((which == 1) ? A1 : A2);
  const unsigned short* Bw = W + (size_t)which * (1u << 20);
  int n0 = qkv ? (n0g & 1023) : n0g;
  int quad = lane >> 4, c = lane & 15;
  int sw8 = c & 7;

  f32x4 acc[4][NI] = {};

  int srow = lane >> 3;                         // row-in-8 this lane writes
  int sseg = ((lane & 7) ^ srow) * 8;           // pre-swizzled source seg (shorts)
  const unsigned short* Asrc = A  + (size_t)(m0 + w * 32      + srow) * K + sseg;
  const unsigned short* Bsrc = Bw + (size_t)(n0 + w * NI * 8  + srow) * K + sseg;

  for (int k0 = 0; k0 < K; k0 += 64) {
    __syncthreads();                            // prev tile's reads done
#pragma unroll
    for (int i = 0; i < 4; i++)
      gld16(Asrc + (size_t)i * 8 * K + k0, As + (w * 32 + i * 8) * 64);
#pragma unroll
    for (int i = 0; i < NI; i++)
      gld16(Bsrc + (size_t)i * 8 * K + k0, Bs + (w * NI * 8 + i * 8) * 64);
    asm volatile("s_waitcnt vmcnt(0)" ::: "memory");
    __syncthreads();                            // all waves' tiles landed

#pragma unroll
    for (int ks = 0; ks < 2; ks++) {
      short8 af[4], bf_[NI];
      int goff = ((quad | (ks << 2)) ^ sw8) * 8;   // swizzled granule
#pragma unroll
      for (int i = 0; i < 4; i++)
        af[i] = load8(As + (wm + i * 16 + c) * 64 + goff);
#pragma unroll
      for (int ni = 0; ni < NI; ni++)
        bf_[ni] = load8(Bs + (wn + ni * 16 + c) * 64 + goff);
#pragma unroll
      for (int mi = 0; mi < 4; mi++)
#pragma unroll
        for (int ni = 0; ni < NI; ni++)
          acc[mi][ni] = __builtin_amdgcn_mfma_f32_16x16x32_bf16(af[mi], bf_[ni], acc[mi][ni], 0, 0, 0);
    }
  }

  int flags = qkv ? ((which == 0) ? 3 : 1) : 0;
#pragma unroll
  for (int mi = 0; mi < 4; mi++) {
#pragma unroll
    for (int ni = 0; ni < NI; ni++) {
      int col = n0g + wn + ni * 16 + c;
      float bv = bias[col];
#pragma unroll
      for (int r = 0; r < 4; r++) {
        int row = m0 + wm + mi * 16 + quad * 4 + r;
        float val = acc[mi][ni][r] + bv;
        if (flags & 2) val *= 0.125f;   // fold 1/sqrt(64) into q
        if (flags & 1) ((unsigned short*)Cv)[(size_t)row * ldc + col] = f2bf(val);
        else           ((float*)Cv)[(size_t)row * ldc + col] = val;
      }
    }
  }
}

// ---------------------------------------------------------------------------
// One-time V transpose: Vt[bh][d][s] = Vproj[s][b][h*64+d].  Lets attn stage V
// with linear async copies instead of 16 scalar LDS writes per thread per chunk.
__global__ __launch_bounds__(256) void transpose_v(const unsigned short* __restrict__ QKV,
                                                   unsigned short* __restrict__ Vt) {
  __shared__ unsigned short T[64 * 68];   // [d][s_local], stride 68 (8B-aligned rows)
  int bh = blockIdx.y;
  int b = bh >> 4, h = bh & 15;
  int s0 = blockIdx.x * 64;
  int t = threadIdx.x;
  int sl = t >> 2, seg = (t & 3) * 16;
  const unsigned short* src = QKV + ((size_t)((s0 + sl) * 2 + b)) * 3072 + 2048 + h * 64 + seg;
  V16 a0, a1;
  a0.f4 = *(const float4*)(src);
  a1.f4 = *(const float4*)(src + 8);
#pragma unroll
  for (int j = 0; j < 8; j++) T[(seg + j) * 68 + sl] = a0.us[j];
#pragma unroll
  for (int j = 0; j < 8; j++) T[(seg + 8 + j) * 68 + sl] = a1.us[j];
  __syncthreads();
  int dl = t >> 2, s2 = (t & 3) * 16;
  const unsigned short* tr = T + dl * 68 + s2;
  V16 o0, o1;
  o0.u64[0] = *(const unsigned long long*)(tr);
  o0.u64[1] = *(const unsigned long long*)(tr + 4);
  o1.u64[0] = *(const unsigned long long*)(tr + 8);
  o1.u64[1] = *(const unsigned long long*)(tr + 12);
  unsigned short* dst = Vt + ((size_t)bh * 64 + dl) * 2048 + s0 + s2;
  st16(dst, o0); st16(dst + 8, o1);
}

// ---------------------------------------------------------------------------
// Fused attention: block = (bh, 128-row T tile), 4 waves x 32 rows.
// Pass 1: row sum-of-exp (scores bounded, no max subtraction).
// Pass 2: recompute scores, p = exp(s)/l, nontemporal probs store, P->LDS bf16,
//         PV MFMA with pre-transposed V.
// K/Vt chunks double-buffered via global_load_lds: next chunk issued right after
// the barrier, so a full chunk of MFMA/exp hides the HBM latency.
__global__ __launch_bounds__(256, 2) void attn_fused(
    const unsigned short* __restrict__ QKV,  // [4096][3072] bf16, q pre-scaled
    const unsigned short* __restrict__ Vt,   // [32][64][2048] bf16
    float* __restrict__ probs,               // [B*H, T, S] fp32
    unsigned short* __restrict__ attnO)      // [4096][1024] bf16
{
  __shared__ unsigned short Qs[128 * LDT];   // padded, reg-staged once
  __shared__ unsigned short Ks[2][64 * 64];  // linear, source-swizzled
  __shared__ unsigned short Vts[2][64 * 64]; // linear, source-swizzled, rows=d
  __shared__ unsigned short Ps[128 * LDT];   // padded

  int tid = threadIdx.x, lane = tid & 63, w = tid >> 6;
  int bh = blockIdx.x >> 4;
  int tt = blockIdx.x & 15;
  int b = bh >> 4, h = bh & 15;
  int t0 = tt * 128;
  int quad = lane >> 4, c = lane & 15;
  int rbase = w * 32;
  int sw8 = c & 7;

  // stage Q tile: 128 rows x 64 cols (padded LDT, 2-way alias = free)
  {
    int row = tid >> 1, lk = (tid & 1) * 32;
    const unsigned short* src = QKV + ((size_t)((t0 + row) * 2 + b)) * 3072 + h * 64 + lk;
    V16 v0, v1, v2, v3;
    v0.f4 = *(const float4*)(src);
    v1.f4 = *(const float4*)(src + 8);
    v2.f4 = *(const float4*)(src + 16);
    v3.f4 = *(const float4*)(src + 24);
    unsigned short* dst = Qs + row * LDT + lk;
    st16(dst, v0); st16(dst + 8, v1); st16(dst + 16, v2); st16(dst + 24, v3);
  }

  int srow = lane >> 3;
  int srs = ((lane & 7) ^ srow) * 8;   // pre-swizzled source seg
  const unsigned short* Kbase = QKV + (size_t)b * 3072 + 1024 + h * 64 + srs + (size_t)srow * 6144;
  const unsigned short* Vbase = Vt + ((size_t)bh * 64 + srow) * 2048 + srs;

  float l_part[2][4] = {};

  // ---- pass 1: sum of exp per row ----
  int cur = 0;
#pragma unroll
  for (int i = 0; i < 2; i++)
    gld16(Kbase + (size_t)(w * 16 + i * 8) * 6144, &Ks[0][(w * 16 + i * 8) * 64]);

  for (int s0 = 0; s0 < 2048; s0 += 64) {
    asm volatile("s_waitcnt vmcnt(0)" ::: "memory");
    __syncthreads();                     // Ks[cur] landed; prev compute done
    if (s0 < 1984) {
#pragma unroll
      for (int i = 0; i < 2; i++)
        gld16(Kbase + (size_t)(s0 + 64 + w * 16 + i * 8) * 6144,
              &Ks[cur ^ 1][(w * 16 + i * 8) * 64]);
    }

    f32x4 sc[2][4] = {};
    const unsigned short* Ab = Qs + (rbase + c) * LDT + quad * 8;
    const unsigned short* Kc = Ks[cur];
#pragma unroll
    for (int ks = 0; ks < 2; ks++) {
      short8 af[2], bfr[4];
      af[0] = load8(Ab + ks * 32);
      af[1] = load8(Ab + 16 * LDT + ks * 32);
      int goff = ((quad | (ks << 2)) ^ sw8) * 8;
#pragma unroll
      for (int ni = 0; ni < 4; ni++)
        bfr[ni] = load8(Kc + (ni * 16 + c) * 64 + goff);
#pragma unroll
      for (int mi = 0; mi < 2; mi++)
#pragma unroll
        for (int ni = 0; ni < 4; ni++)
          sc[mi][ni] = __builtin_amdgcn_mfma_f32_16x16x32_bf16(af[mi], bfr[ni], sc[mi][ni], 0, 0, 0);
    }
#pragma unroll
    for (int mi = 0; mi < 2; mi++)
#pragma unroll
      for (int r = 0; r < 4; r++)
        l_part[mi][r] += __expf(sc[mi][0][r]) + __expf(sc[mi][1][r]) +
                         __expf(sc[mi][2][r]) + __expf(sc[mi][3][r]);
    cur ^= 1;
  }

  float rl[2][4];
#pragma unroll
  for (int mi = 0; mi < 2; mi++)
#pragma unroll
    for (int r = 0; r < 4; r++) {
      float s = l_part[mi][r];
      s += __shfl_xor(s, 1); s += __shfl_xor(s, 2);
      s += __shfl_xor(s, 4); s += __shfl_xor(s, 8);
      rl[mi][r] = 1.0f / s;
    }

  f32x4 acc_o[2][4] = {};
  size_t prow_base = ((size_t)bh * 2048 + t0) * 2048;

  // ---- pass 2: probs + PV ----
  // pass-1's last chunk used Ks[1], so priming Ks[0]/Vts[0] here is race-free.
  cur = 0;
#pragma unroll
  for (int i = 0; i < 2; i++) {
    gld16(Kbase + (size_t)(w * 16 + i * 8) * 6144, &Ks[0][(w * 16 + i * 8) * 64]);
    gld16(Vbase + (size_t)(w * 16 + i * 8) * 2048, &Vts[0][(w * 16 + i * 8) * 64]);
  }

  for (int s0 = 0; s0 < 2048; s0 += 64) {
    asm volatile("s_waitcnt vmcnt(0)" ::: "memory");
    __syncthreads();                     // bufs[cur] landed; prev PV done
    if (s0 < 1984) {
#pragma unroll
      for (int i = 0; i < 2; i++) {
        gld16(Kbase + (size_t)(s0 + 64 + w * 16 + i * 8) * 6144,
              &Ks[cur ^ 1][(w * 16 + i * 8) * 64]);
        gld16(Vbase + (size_t)(w * 16 + i * 8) * 2048 + (s0 + 64),
              &Vts[cur ^ 1][(w * 16 + i * 8) * 64]);
      }
    }

    f32x4 sc[2][4] = {};
    const unsigned short* Ab = Qs + (rbase + c) * LDT + quad * 8;
    const unsigned short* Kc = Ks[cur];
#pragma unroll
    for (int ks = 0; ks < 2; ks++) {
      short8 af[2], bfr[4];
      af[0] = load8(Ab + ks * 32);
      af[1] = load8(Ab + 16 * LDT + ks * 32);
      int goff = ((quad | (ks << 2)) ^ sw8) * 8;
#pragma unroll
      for (int ni = 0; ni < 4; ni++)
        bfr[ni] = load8(Kc + (ni * 16 + c) * 64 + goff);
#pragma unroll
      for (int mi = 0; mi < 2; mi++)
#pragma unroll
        for (int ni = 0; ni < 4; ni++)
          sc[mi][ni] = __builtin_amdgcn_mfma_f32_16x16x32_bf16(af[mi], bfr[ni], sc[mi][ni], 0, 0, 0);
    }

#pragma unroll
    for (int mi = 0; mi < 2; mi++)
#pragma unroll
      for (int ni = 0; ni < 4; ni++) {
        int cloc = ni * 16 + c;
#pragma unroll
        for (int r = 0; r < 4; r++) {
          float p = __expf(sc[mi][ni][r]) * rl[mi][r];
          int rloc = rbase + mi * 16 + quad * 4 + r;
          __builtin_nontemporal_store(p, probs + prow_base + (size_t)rloc * 2048 + s0 + cloc);
          Ps[rloc * LDT + cloc] = f2bf(p);
        }
      }
    __syncthreads();                     // Ps ready

    const unsigned short* Ab2 = Ps + (rbase + c) * LDT + quad * 8;
    const unsigned short* Vc = Vts[cur];
#pragma unroll
    for (int ks = 0; ks < 2; ks++) {
      short8 af[2], bfr[4];
      af[0] = load8(Ab2 + ks * 32);
      af[1] = load8(Ab2 + 16 * LDT + ks * 32);
      int goff = ((quad | (ks << 2)) ^ sw8) * 8;
#pragma unroll
      for (int ni = 0; ni < 4; ni++)
        bfr[ni] = load8(Vc + (ni * 16 + c) * 64 + goff);
#pragma unroll
      for (int mi = 0; mi < 2; mi++)
#pragma unroll
        for (int ni = 0; ni < 4; ni++)
          acc_o[mi][ni] = __builtin_amdgcn_mfma_f32_16x16x32_bf16(af[mi], bfr[ni], acc_o[mi][ni], 0, 0, 0);
    }
    cur ^= 1;
  }

  // write O (bf16) for the out-projection GEMM
#pragma unroll
  for (int mi = 0; mi < 2; mi++)
#pragma unroll
    for (int ni = 0; ni < 4; ni++)
#pragma unroll
      for (int r = 0; r < 4; r++) {
        int t = t0 + rbase + mi * 16 + quad * 4 + r;
        attnO[(size_t)(t * 2 + b) * 1024 + h * 64 + ni * 16 + c] = f2bf(acc_o[mi][ni][r]);
      }
}

// ---------------------------------------------------------------------------
extern "C" void kernel_launch(void* const* d_in, const int* in_sizes, int n_in,
                              void* d_out, int out_size, void* d_ws, size_t ws_size,
                              hipStream_t stream) {
  (void)in_sizes; (void)n_in; (void)out_size; (void)ws_size;
  const float* q_in  = (const float*)d_in[0];
  const float* k_in  = (const float*)d_in[1];
  const float* v_in  = (const float*)d_in[2];
  const float* w_in  = (const float*)d_in[3];
  const float* b_in  = (const float*)d_in[4];
  const float* w_out = (const float*)d_in[5];
  const float* b_out = (const float*)d_in[6];

  float* out0  = (float*)d_out;
  float* probs = out0 + (size_t)4096 * 1024;

  unsigned short* Xq  = (unsigned short*)d_ws;
  unsigned short* Xk  = Xq + (size_t)4096 * 1024;
  unsigned short* Xv  = Xk + (size_t)4096 * 1024;
  unsigned short* Wi  = Xv + (size_t)4096 * 1024;
  unsigned short* Wo  = Wi + (size_t)3072 * 1024;
  unsigned short* QKV = Wo + (size_t)1024 * 1024;   // [4096][3072]
  unsigned short* AO  = QKV + (size_t)4096 * 3072;  // [4096][1024]
  unsigned short* Vt  = AO + (size_t)4096 * 1024;   // [32][64][2048]

  cvt_all<<<dim3(4096, 5), 256, 0, stream>>>(q_in, k_in, v_in, w_in, w_out,
                                             Xq, Xk, Xv, Wi, Wo);

  // fused QKV projection: [4096x1024]x[1024x1024] x3 -> QKV [4096][3072]
  gemm_bt<128><<<dim3(24, 32), 256, 0, stream>>>(Xq, Xk, Xv, Wi, b_in, QKV, 1024, 3072, 1);

  transpose_v<<<dim3(32, 32), 256, 0, stream>>>(QKV, Vt);

  attn_fused<<<512, 256, 0, stream>>>(QKV, Vt, probs, AO);

  // out projection, BN=64 tile -> 512 blocks (2/CU)
  gemm_bt<64><<<dim3(16, 32), 256, 0, stream>>>(AO, AO, AO, Wo, b_out, (void*)out0, 1024, 1024, 0);
}